// Round 4
// baseline (320.827 us; speedup 1.0000x reference)
//
#include <hip/hip_runtime.h>

// Problem constants (B=64 batches, n=64 nodes/batch, H=128, epg=2048 edges/batch)
#define NB 64
#define NPB 64
#define HD 128
#define EPB 2048
#define NNODE 4096     // NB*NPB
#define KK 52          // ceil(0.8*64)
#define NKOUT 3328     // NB*KK
#define NEG 0.01f

typedef __attribute__((ext_vector_type(8))) __bf16 bf16x8;
typedef __attribute__((ext_vector_type(16))) float floatx16;

__device__ __forceinline__ float lrelu(float v){ return v > 0.f ? v : NEG*v; }

// exact 3-way bf16 split: v ~= b1 + b2 + b3 (24 mantissa bits)
__device__ __forceinline__ void split3(float v, __bf16* o1, __bf16* o2, __bf16* o3){
  __bf16 b1 = (__bf16)v;
  float r1 = v - (float)b1;
  __bf16 b2 = (__bf16)r1;
  float r2 = r1 - (float)b2;
  *o1 = b1; *o2 = b2; *o3 = (__bf16)r2;
}

// LDS layout: row pitch 40 bf16 (80B, 16B-aligned); XOR swizzle on 16B chunks
#define SW(r, ko) ((r)*40 + ((ko) ^ ((((r)>>3)&3) << 3)))

// ---------------- zero-fill (A2 off-block region) ----------------
__global__ void k_zero4(float4* __restrict__ p, int n4){
  int i = blockIdx.x*256 + threadIdx.x;
  if (i < n4) p[i] = make_float4(0.f,0.f,0.f,0.f);
}

// ---------------- build dense per-batch A (normalized) + multiplicity M ----------------
__global__ __launch_bounds__(256) void k_build(const int* __restrict__ ei, const float* __restrict__ w,
                                               float* __restrict__ A_g, float* __restrict__ M_g){
  __shared__ float Ws[4096];
  __shared__ float Mc[4096];
  __shared__ float dv[64];
  int b = blockIdx.x, tid = threadIdx.x;
  for (int i = tid; i < 4096; i += 256){ Ws[i] = 0.f; Mc[i] = 0.f; }
  __syncthreads();
  const int* r0 = ei + b*EPB;
  const int* c0 = ei + NB*EPB + b*EPB;
  const float* w0 = w + b*EPB;
  int base = b*NPB;
  for (int e = tid; e < EPB; e += 256){
    int r = r0[e] - base, c = c0[e] - base;
    atomicAdd(&Ws[r*64 + c], w0[e]);
    atomicAdd(&Mc[r*64 + c], 1.f);
  }
  if (tid < 64){ atomicAdd(&Ws[tid*64 + tid], 1.f); atomicAdd(&Mc[tid*64 + tid], 1.f); }
  __syncthreads();
  if (tid < 64){
    float d = 0.f;
    for (int r = 0; r < 64; r++) d += Ws[r*64 + tid];   // deg over col
    dv[tid] = d > 0.f ? rsqrtf(fmaxf(d, 1e-12f)) : 0.f;
  }
  __syncthreads();
  for (int i = tid; i < 4096; i += 256){
    int r = i >> 6, c = i & 63;
    A_g[b*4096 + i] = dv[r]*Ws[i]*dv[c];
    M_g[b*4096 + i] = Mc[i];
  }
}

// ---------------- double hop: out = A^T (A^T v), per-batch, f-split over blockIdx.y ----------------
__global__ __launch_bounds__(256) void k_hop2(const float* __restrict__ A_g, const float* __restrict__ v_in,
                                              float* __restrict__ v_out){
  __shared__ __align__(16) float A[4096];
  __shared__ __align__(16) float V[4096];
  __shared__ __align__(16) float T[4096];
  int b = blockIdx.x, f0 = blockIdx.y*64, tid = threadIdx.x;
  for (int i = tid*4; i < 4096; i += 1024)
    *(float4*)&A[i] = *(const float4*)(A_g + b*4096 + i);
  for (int i = tid*4; i < 4096; i += 1024){
    int r = i >> 6, j = i & 63;
    *(float4*)&V[i] = *(const float4*)(v_in + (size_t)b*8192 + r*128 + f0 + j);
  }
  __syncthreads();
  int tc = (tid & 15)*4, tf = (tid >> 4)*4;
  float acc[4][4];
  #pragma unroll
  for (int i = 0; i < 4; i++)
    #pragma unroll
    for (int j = 0; j < 4; j++) acc[i][j] = 0.f;
  for (int r = 0; r < 64; r++){
    float4 a4 = *(const float4*)&A[r*64 + tc];
    float4 v4 = *(const float4*)&V[r*64 + tf];
    float a_[4] = {a4.x,a4.y,a4.z,a4.w};
    float v_[4] = {v4.x,v4.y,v4.z,v4.w};
    #pragma unroll
    for (int ci = 0; ci < 4; ci++)
      #pragma unroll
      for (int fj = 0; fj < 4; fj++) acc[ci][fj] += a_[ci]*v_[fj];
  }
  #pragma unroll
  for (int ci = 0; ci < 4; ci++)
    *(float4*)&T[(tc+ci)*64 + tf] = make_float4(acc[ci][0], acc[ci][1], acc[ci][2], acc[ci][3]);
  __syncthreads();
  #pragma unroll
  for (int i = 0; i < 4; i++)
    #pragma unroll
    for (int j = 0; j < 4; j++) acc[i][j] = 0.f;
  for (int r = 0; r < 64; r++){
    float4 a4 = *(const float4*)&A[r*64 + tc];
    float4 t4 = *(const float4*)&T[r*64 + tf];
    float a_[4] = {a4.x,a4.y,a4.z,a4.w};
    float t_[4] = {t4.x,t4.y,t4.z,t4.w};
    #pragma unroll
    for (int ci = 0; ci < 4; ci++)
      #pragma unroll
      for (int fj = 0; fj < 4; fj++) acc[ci][fj] += a_[ci]*t_[fj];
  }
  #pragma unroll
  for (int ci = 0; ci < 4; ci++)
    *(float4*)(v_out + (size_t)b*8192 + (tc+ci)*128 + f0 + tf) =
      make_float4(acc[ci][0], acc[ci][1], acc[ci][2], acc[ci][3]);
}

// ---------------- MFMA fp32-faithful GEMM (bf16x6): C = act(A @ W), 64x64 tile ----------------
__global__ __launch_bounds__(256) void k_mgemm(const float* __restrict__ A, const float* __restrict__ W,
                                               float* __restrict__ C, int K, int M,
                                               long az, long wz, long cz, int leaky){
  int z = blockIdx.z;
  A += (size_t)z*az; W += (size_t)z*wz; C += (size_t)z*cz;
  __shared__ __bf16 Ah[3][2560];
  __shared__ __bf16 Wt[3][2560];
  int tid = threadIdx.x;
  int i0 = blockIdx.y*64, j0 = blockIdx.x*64;
  int sar = tid >> 2, sako = (tid & 3)*8;    // A staging: row, k-offset
  int swn = tid & 63, swk = (tid >> 6)*8;    // W staging: col, k-offset
  int w = tid >> 6, L = tid & 63;
  int m = L & 31, half = L >> 5;
  int rA = 32*(w & 1) + m;
  int rB = 32*(w >> 1) + m;
  floatx16 acc;
  #pragma unroll
  for (int i = 0; i < 16; i++) acc[i] = 0.f;
  for (int k0 = 0; k0 < K; k0 += 32){
    {
      const float* ap = A + (size_t)(i0 + sar)*K + k0 + sako;
      float4 v0 = *(const float4*)ap;
      float4 v1 = *(const float4*)(ap + 4);
      float vv[8] = {v0.x,v0.y,v0.z,v0.w,v1.x,v1.y,v1.z,v1.w};
      bf16x8 p1, p2, p3;
      #pragma unroll
      for (int j = 0; j < 8; j++){ __bf16 b1,b2,b3; split3(vv[j],&b1,&b2,&b3); p1[j]=b1; p2[j]=b2; p3[j]=b3; }
      *(bf16x8*)&Ah[0][SW(sar,sako)] = p1;
      *(bf16x8*)&Ah[1][SW(sar,sako)] = p2;
      *(bf16x8*)&Ah[2][SW(sar,sako)] = p3;
    }
    {
      bf16x8 p1, p2, p3;
      #pragma unroll
      for (int j = 0; j < 8; j++){
        float wv = W[(size_t)(k0 + swk + j)*M + j0 + swn];
        __bf16 b1,b2,b3; split3(wv,&b1,&b2,&b3); p1[j]=b1; p2[j]=b2; p3[j]=b3;
      }
      *(bf16x8*)&Wt[0][SW(swn,swk)] = p1;
      *(bf16x8*)&Wt[1][SW(swn,swk)] = p2;
      *(bf16x8*)&Wt[2][SW(swn,swk)] = p3;
    }
    __syncthreads();
    #pragma unroll
    for (int kg = 0; kg < 2; kg++){
      int ko = kg*16 + half*8;
      bf16x8 a1 = *(const bf16x8*)&Ah[0][SW(rA,ko)];
      bf16x8 a2 = *(const bf16x8*)&Ah[1][SW(rA,ko)];
      bf16x8 a3 = *(const bf16x8*)&Ah[2][SW(rA,ko)];
      bf16x8 b1 = *(const bf16x8*)&Wt[0][SW(rB,ko)];
      bf16x8 b2 = *(const bf16x8*)&Wt[1][SW(rB,ko)];
      bf16x8 b3 = *(const bf16x8*)&Wt[2][SW(rB,ko)];
      acc = __builtin_amdgcn_mfma_f32_32x32x16_bf16(a1,b1,acc,0,0,0);
      acc = __builtin_amdgcn_mfma_f32_32x32x16_bf16(a1,b2,acc,0,0,0);
      acc = __builtin_amdgcn_mfma_f32_32x32x16_bf16(a2,b1,acc,0,0,0);
      acc = __builtin_amdgcn_mfma_f32_32x32x16_bf16(a1,b3,acc,0,0,0);
      acc = __builtin_amdgcn_mfma_f32_32x32x16_bf16(a3,b1,acc,0,0,0);
      acc = __builtin_amdgcn_mfma_f32_32x32x16_bf16(a2,b2,acc,0,0,0);
    }
    __syncthreads();
  }
  int col = j0 + 32*(w >> 1) + m;
  int row0 = i0 + 32*(w & 1) + 4*half;
  #pragma unroll
  for (int reg = 0; reg < 16; reg++){
    int row = row0 + (reg & 3) + 8*(reg >> 2);
    float v = acc[reg];
    if (leaky) v = lrelu(v);
    C[(size_t)row*M + col] = v;
  }
}

// ---------------- MFMA W1 GEMM, folded K=384, h=[a,q,a*q] synthesized in staging ----------------
// z=0: query = q0 (per-node). z=1: query = tgt[batch] broadcast.
__global__ __launch_bounds__(256) void k_mgemm_h(const float* __restrict__ a_buf, const float* __restrict__ q0,
                                                 const float* __restrict__ tgt, const float* __restrict__ W1,
                                                 float* __restrict__ C){
  int z = blockIdx.z;
  const float* Az = a_buf + (size_t)z*NNODE*HD;
  const float* Wz = W1 + (size_t)z*512*256;
  float* Cz = C + (size_t)z*NNODE*256;
  __shared__ __bf16 Ah[3][2560];
  __shared__ __bf16 Wt[3][2560];
  int tid = threadIdx.x;
  int i0 = blockIdx.y*64, j0 = blockIdx.x*64;
  int sar = tid >> 2, sako = (tid & 3)*8;
  int swn = tid & 63, swk = (tid >> 6)*8;
  int w = tid >> 6, L = tid & 63;
  int m = L & 31, half = L >> 5;
  int rA = 32*(w & 1) + m;
  int rB = 32*(w >> 1) + m;
  int gi = i0 + sar;
  const float* arow = Az + (size_t)gi*HD;
  const float* qrow = (z == 0) ? q0 + (size_t)gi*HD : tgt + (size_t)(gi >> 6)*HD;
  floatx16 acc;
  #pragma unroll
  for (int i = 0; i < 16; i++) acc[i] = 0.f;
  for (int k0 = 0; k0 < 384; k0 += 32){
    {
      int kk = k0 + sako, seg = kk >> 7, kl = kk & 127;
      float vv[8];
      if (seg == 0){
        float4 v0 = *(const float4*)(arow + kl);
        float4 v1 = *(const float4*)(arow + kl + 4);
        vv[0]=v0.x; vv[1]=v0.y; vv[2]=v0.z; vv[3]=v0.w; vv[4]=v1.x; vv[5]=v1.y; vv[6]=v1.z; vv[7]=v1.w;
      } else if (seg == 1){
        float4 v0 = *(const float4*)(qrow + kl);
        float4 v1 = *(const float4*)(qrow + kl + 4);
        vv[0]=v0.x; vv[1]=v0.y; vv[2]=v0.z; vv[3]=v0.w; vv[4]=v1.x; vv[5]=v1.y; vv[6]=v1.z; vv[7]=v1.w;
      } else {
        float4 a0 = *(const float4*)(arow + kl);
        float4 a1 = *(const float4*)(arow + kl + 4);
        float4 q0v = *(const float4*)(qrow + kl);
        float4 q1v = *(const float4*)(qrow + kl + 4);
        vv[0]=a0.x*q0v.x; vv[1]=a0.y*q0v.y; vv[2]=a0.z*q0v.z; vv[3]=a0.w*q0v.w;
        vv[4]=a1.x*q1v.x; vv[5]=a1.y*q1v.y; vv[6]=a1.z*q1v.z; vv[7]=a1.w*q1v.w;
      }
      bf16x8 p1, p2, p3;
      #pragma unroll
      for (int j = 0; j < 8; j++){ __bf16 b1,b2,b3; split3(vv[j],&b1,&b2,&b3); p1[j]=b1; p2[j]=b2; p3[j]=b3; }
      *(bf16x8*)&Ah[0][SW(sar,sako)] = p1;
      *(bf16x8*)&Ah[1][SW(sar,sako)] = p2;
      *(bf16x8*)&Ah[2][SW(sar,sako)] = p3;
    }
    {
      bf16x8 p1, p2, p3;
      #pragma unroll
      for (int j = 0; j < 8; j++){
        int kr = k0 + swk + j;
        const float* wp = Wz + (size_t)kr*256 + j0 + swn;
        float wv;
        if (kr < 128)      wv = wp[0] + wp[65536];        // W1a + W1c
        else if (kr < 256) wv = wp[0] - wp[32768];        // W1b - W1c
        else               wv = wp[32768];                // W1d
        __bf16 b1,b2,b3; split3(wv,&b1,&b2,&b3); p1[j]=b1; p2[j]=b2; p3[j]=b3;
      }
      *(bf16x8*)&Wt[0][SW(swn,swk)] = p1;
      *(bf16x8*)&Wt[1][SW(swn,swk)] = p2;
      *(bf16x8*)&Wt[2][SW(swn,swk)] = p3;
    }
    __syncthreads();
    #pragma unroll
    for (int kg = 0; kg < 2; kg++){
      int ko = kg*16 + half*8;
      bf16x8 a1 = *(const bf16x8*)&Ah[0][SW(rA,ko)];
      bf16x8 a2 = *(const bf16x8*)&Ah[1][SW(rA,ko)];
      bf16x8 a3 = *(const bf16x8*)&Ah[2][SW(rA,ko)];
      bf16x8 b1 = *(const bf16x8*)&Wt[0][SW(rB,ko)];
      bf16x8 b2 = *(const bf16x8*)&Wt[1][SW(rB,ko)];
      bf16x8 b3 = *(const bf16x8*)&Wt[2][SW(rB,ko)];
      acc = __builtin_amdgcn_mfma_f32_32x32x16_bf16(a1,b1,acc,0,0,0);
      acc = __builtin_amdgcn_mfma_f32_32x32x16_bf16(a1,b2,acc,0,0,0);
      acc = __builtin_amdgcn_mfma_f32_32x32x16_bf16(a2,b1,acc,0,0,0);
      acc = __builtin_amdgcn_mfma_f32_32x32x16_bf16(a1,b3,acc,0,0,0);
      acc = __builtin_amdgcn_mfma_f32_32x32x16_bf16(a3,b1,acc,0,0,0);
      acc = __builtin_amdgcn_mfma_f32_32x32x16_bf16(a2,b2,acc,0,0,0);
    }
    __syncthreads();
  }
  int col = j0 + 32*(w >> 1) + m;
  int row0 = i0 + 32*(w & 1) + 4*half;
  #pragma unroll
  for (int reg = 0; reg < 16; reg++){
    int row = row0 + (reg & 3) + 8*(reg >> 2);
    Cz[(size_t)row*256 + col] = lrelu(acc[reg]);
  }
}

// ---------------- fused W3 dot + per-batch softmax ----------------
__global__ __launch_bounds__(256) void k_w3sm(const float* __restrict__ h2, const float* __restrict__ W3,
                                              float* __restrict__ outF){
  int b = blockIdx.x, z = blockIdx.z;
  int wave = threadIdx.x >> 6, lane = threadIdx.x & 63;
  __shared__ float lg[64];
  const float* w = W3 + (size_t)z*HD;
  float w0 = w[lane], w1 = w[lane + 64];
  #pragma unroll 4
  for (int i = 0; i < 16; i++){
    int row = wave*16 + i;
    const float* h = h2 + ((size_t)z*NNODE + b*64 + row)*HD;
    float v = h[lane]*w0 + h[lane + 64]*w1;
    #pragma unroll
    for (int off = 32; off; off >>= 1) v += __shfl_down(v, off);
    if (lane == 0) lg[row] = lrelu(v);
  }
  __syncthreads();
  if (threadIdx.x < 64){
    float l = lg[threadIdx.x];
    float m = l;
    #pragma unroll
    for (int off = 32; off; off >>= 1) m = fmaxf(m, __shfl_xor(m, off));
    float e = expf(l - m);
    float s = e;
    #pragma unroll
    for (int off = 32; off; off >>= 1) s += __shfl_xor(s, off);
    outF[z*NNODE + b*64 + threadIdx.x] = e/s;
  }
}

// ---------------- edge softmax (multiplicity-weighted) + S + agg ----------------
__global__ __launch_bounds__(256) void k_edge(const float* __restrict__ M_g, const float* __restrict__ fb,
                                              const float* __restrict__ x, float* __restrict__ S_g,
                                              float* __restrict__ agg){
  __shared__ __align__(16) float Mc[4096];
  __shared__ __align__(16) float xb[8192];
  __shared__ float f1s[64], f2s[64];
  int b = blockIdx.x, tid = threadIdx.x;
  for (int i = tid; i < 4096; i += 256) Mc[i] = M_g[b*4096 + i];
  for (int i = tid*4; i < 8192; i += 1024)
    *(float4*)&xb[i] = *(const float4*)(x + (size_t)b*8192 + i);
  if (tid < 64) f1s[tid] = fb[b*64 + tid];
  else if (tid < 128) f2s[tid - 64] = fb[NNODE + b*64 + (tid - 64)];
  __syncthreads();
  int c = tid >> 2, sub = tid & 3;
  float m = -1e30f;
  for (int r = sub; r < 64; r += 4)
    if (Mc[r*64 + c] > 0.f) m = fmaxf(m, lrelu(f1s[c] + f2s[r]));
  m = fmaxf(m, __shfl_xor(m, 1));
  m = fmaxf(m, __shfl_xor(m, 2));
  float s = 0.f;
  for (int r = sub; r < 64; r += 4){
    float mc = Mc[r*64 + c];
    if (mc > 0.f) s += mc*expf(lrelu(f1s[c] + f2s[r]) - m);
  }
  s += __shfl_xor(s, 1);
  s += __shfl_xor(s, 2);
  for (int r = sub; r < 64; r += 4){
    float mc = Mc[r*64 + c];
    float v = 0.f;
    if (mc > 0.f) v = mc*expf(lrelu(f1s[c] + f2s[r]) - m)/s;
    Mc[r*64 + c] = v;
  }
  __syncthreads();
  for (int i = tid; i < 4096; i += 256) S_g[b*4096 + i] = Mc[i];
  int tc = (tid & 15)*4, tf = (tid >> 4)*8;
  float acc[4][8];
  #pragma unroll
  for (int i = 0; i < 4; i++)
    #pragma unroll
    for (int j = 0; j < 8; j++) acc[i][j] = 0.f;
  for (int r = 0; r < 64; r++){
    float4 e4 = *(const float4*)&Mc[r*64 + tc];
    float4 x0 = *(const float4*)&xb[r*128 + tf];
    float4 x1 = *(const float4*)&xb[r*128 + tf + 4];
    float e_[4] = {e4.x,e4.y,e4.z,e4.w};
    float x_[8] = {x0.x,x0.y,x0.z,x0.w,x1.x,x1.y,x1.z,x1.w};
    #pragma unroll
    for (int ci = 0; ci < 4; ci++)
      #pragma unroll
      for (int fj = 0; fj < 8; fj++) acc[ci][fj] += e_[ci]*x_[fj];
  }
  #pragma unroll
  for (int ci = 0; ci < 4; ci++){
    *(float4*)(agg + (size_t)b*8192 + (tc+ci)*128 + tf)     = make_float4(acc[ci][0],acc[ci][1],acc[ci][2],acc[ci][3]);
    *(float4*)(agg + (size_t)b*8192 + (tc+ci)*128 + tf + 4) = make_float4(acc[ci][4],acc[ci][5],acc[ci][6],acc[ci][7]);
  }
}

// ---------------- x_c = 0.5*(leaky(x+y0)+leaky(x+y1)) ----------------
__global__ void k_xc(const float* __restrict__ x, const float* __restrict__ y, float* __restrict__ xc){
  int i = blockIdx.x*256 + threadIdx.x;
  float xv = x[i];
  xc[i] = 0.5f*(lrelu(xv + y[i]) + lrelu(xv + y[NNODE*HD + i]));
}

// ---------------- fused: cluster-score softmax + exact top-52 + x_out gather ----------------
__global__ __launch_bounds__(256) void k_pool(const float* __restrict__ gb, const float* __restrict__ x,
                                              int* __restrict__ pidx, float* __restrict__ outB,
                                              float* __restrict__ outP, float* __restrict__ outX){
  int b = blockIdx.x, tid = threadIdx.x;
  __shared__ int pi[KK];
  __shared__ float pv[KK];
  if (tid < 64){
    float l = gb[b*64 + tid] + gb[NNODE + b*64 + tid];
    float m = l;
    #pragma unroll
    for (int off = 32; off; off >>= 1) m = fmaxf(m, __shfl_xor(m, off));
    float e = expf(l - m);
    float sm = e;
    #pragma unroll
    for (int off = 32; off; off >>= 1) sm += __shfl_xor(sm, off);
    float s = e/sm;
    int lane = tid;
    for (int t = 0; t < KK; t++){
      float v = s; int idx = lane;
      #pragma unroll
      for (int off = 32; off; off >>= 1){
        float ov = __shfl_xor(v, off); int oi = __shfl_xor(idx, off);
        if (ov > v || (ov == v && oi < idx)){ v = ov; idx = oi; }
      }
      if (lane == 0){
        pi[t] = idx; pv[t] = v;
        pidx[b*KK + t] = idx;
        outB[b*KK + t] = (float)b;
        outP[b*KK + t] = (float)(b*64 + idx);
      }
      if (lane == idx) s = -1e30f;
    }
  }
  __syncthreads();
  for (int o = tid*4; o < KK*HD; o += 1024){
    int j = o >> 7, f = o & 127;
    float4 xv = *(const float4*)(x + ((size_t)b*64 + pi[j])*HD + f);
    float sv = pv[j];
    *(float4*)(outX + (size_t)b*KK*HD + o) = make_float4(xv.x*sv, xv.y*sv, xv.z*sv, xv.w*sv);
  }
}

// ---------------- per-batch A2 block: S_p^T (A S_p), diag=1 ----------------
__global__ __launch_bounds__(256) void k_A2(const float* __restrict__ A_g, const float* __restrict__ S_g,
                                            const int* __restrict__ pidx, float* __restrict__ outA2){
  __shared__ __align__(16) float At[64*68];
  __shared__ __align__(16) float Sp[64*56];
  __shared__ __align__(16) float T[64*56];
  __shared__ int pc[KK];
  int b = blockIdx.x, tid = threadIdx.x;
  if (tid < KK) pc[tid] = pidx[b*KK + tid];
  __syncthreads();
  for (int idx = tid; idx < 4096; idx += 256){
    int i = idx >> 6, k = idx & 63;
    At[k*68 + i] = A_g[b*4096 + idx];
  }
  for (int idx = tid; idx < 4096; idx += 256){
    int k = idx >> 6, t = idx & 63;
    if (t < 56) Sp[k*56 + t] = (t < KK) ? S_g[b*4096 + k*64 + pc[t]] : 0.f;
  }
  __syncthreads();
  if (tid < 224){
    int i0 = (tid/14)*4, t0 = (tid % 14)*4;
    float acc[4][4];
    #pragma unroll
    for (int a = 0; a < 4; a++)
      #pragma unroll
      for (int c = 0; c < 4; c++) acc[a][c] = 0.f;
    for (int k = 0; k < 64; k++){
      float4 a4 = *(const float4*)&At[k*68 + i0];
      float4 s4 = *(const float4*)&Sp[k*56 + t0];
      float a_[4] = {a4.x,a4.y,a4.z,a4.w};
      float s_[4] = {s4.x,s4.y,s4.z,s4.w};
      #pragma unroll
      for (int ii = 0; ii < 4; ii++)
        #pragma unroll
        for (int tt = 0; tt < 4; tt++) acc[ii][tt] += a_[ii]*s_[tt];
    }
    #pragma unroll
    for (int ii = 0; ii < 4; ii++)
      *(float4*)&T[(i0+ii)*56 + t0] = make_float4(acc[ii][0],acc[ii][1],acc[ii][2],acc[ii][3]);
  }
  __syncthreads();
  if (tid < 169){
    int a0 = (tid/13)*4, t0 = (tid % 13)*4;
    float acc[4][4];
    #pragma unroll
    for (int a = 0; a < 4; a++)
      #pragma unroll
      for (int c = 0; c < 4; c++) acc[a][c] = 0.f;
    for (int i = 0; i < 64; i++){
      float4 s4 = *(const float4*)&Sp[i*56 + a0];
      float4 t4 = *(const float4*)&T[i*56 + t0];
      float s_[4] = {s4.x,s4.y,s4.z,s4.w};
      float t_[4] = {t4.x,t4.y,t4.z,t4.w};
      #pragma unroll
      for (int aa = 0; aa < 4; aa++)
        #pragma unroll
        for (int tt = 0; tt < 4; tt++) acc[aa][tt] += s_[aa]*t_[tt];
    }
    #pragma unroll
    for (int aa = 0; aa < 4; aa++)
      #pragma unroll
      for (int tt = 0; tt < 4; tt++){
        int a = a0 + aa, t = t0 + tt;
        float v = (a == t) ? 1.f : acc[aa][tt];
        outA2[(size_t)(b*KK + a)*NKOUT + b*KK + t] = v;
      }
  }
}

extern "C" void kernel_launch(void* const* d_in, const int* in_sizes, int n_in,
                              void* d_out, int out_size, void* d_ws, size_t ws_size,
                              hipStream_t stream){
  const float* x    = (const float*)d_in[0];
  const int*   ei   = (const int*)d_in[1];
  const float* ew   = (const float*)d_in[2];
  const float* tgt  = (const float*)d_in[3];
  const float* Wk   = (const float*)d_in[5];
  const float* W1   = (const float*)d_in[6];
  const float* W2   = (const float*)d_in[7];
  const float* W3   = (const float*)d_in[8];
  const float* linW = (const float*)d_in[9];
  float* out = (float*)d_out;

  float* wf    = (float*)d_ws;
  float* A_g   = wf;                   // 262144
  float* M_g   = A_g + 262144;
  float* S_g   = M_g + 262144;
  float* xq    = S_g + 262144;         // 524288
  float* xq2   = xq + 524288;
  float* aggb  = xq2 + 524288;
  float* xc    = aggb + 524288;
  float* a_buf = xc + 524288;          // 2 x 524288
  float* h1    = a_buf + 1048576;      // 2 x 1048576
  float* h2    = h1 + 2097152;         // 2 x 524288 (also reused for y=agg@linW)
  float* fb    = h2 + 1048576;         // 2 x 4096
  float* gb    = fb + 8192;            // 2 x 4096
  int*   pidx  = (int*)(gb + 8192);    // NKOUT

  float* outX  = out;                          // 3328 x 128
  float* outA2 = out + 425984;                 // 3328 x 3328
  float* outB  = out + 425984 + 11075584;      // 3328
  float* outP  = outB + NKOUT;                 // 3328

  // 1. zero A2 region
  k_zero4<<<dim3(10816), dim3(256), 0, stream>>>((float4*)outA2, 2768896);
  // 2. dense per-batch normalized adjacency + multiplicity
  k_build<<<dim3(64), dim3(256), 0, stream>>>(ei, ew, A_g, M_g);
  // 3. x_q = hop(hop(x))
  k_hop2<<<dim3(64,2), dim3(256), 0, stream>>>(A_g, x, xq);
  // 4. attention pair f (kv=x; q: z0=x_q, z1=target)
  k_mgemm<<<dim3(2,64,2), dim3(256), 0, stream>>>(x, Wk, a_buf, 128, 128, 0L, 16384L, 524288L, 0);
  k_mgemm_h<<<dim3(4,64,2), dim3(256), 0, stream>>>(a_buf, xq, tgt, W1, h1);
  k_mgemm<<<dim3(2,64,2), dim3(256), 0, stream>>>(h1, W2, h2, 256, 128, 1048576L, 32768L, 524288L, 1);
  k_w3sm<<<dim3(64,1,2), dim3(256), 0, stream>>>(h2, W3, fb);
  // 5. edge softmax -> S, agg
  k_edge<<<dim3(64), dim3(256), 0, stream>>>(M_g, fb, x, S_g, aggb);
  // 6. y = agg @ lin_W (2 heads), x_c
  k_mgemm<<<dim3(2,64,2), dim3(256), 0, stream>>>(aggb, linW, h2, 128, 128, 0L, 16384L, 524288L, 0);
  k_xc<<<dim3(2048), dim3(256), 0, stream>>>(x, h2, xc);
  // 7. x_q2 = hop(hop(x_c))
  k_hop2<<<dim3(64,2), dim3(256), 0, stream>>>(A_g, xc, xq2);
  // 8. attention pair g (kv=x_c; q: z0=x_q2, z1=target)
  k_mgemm<<<dim3(2,64,2), dim3(256), 0, stream>>>(xc, Wk + 2*16384, a_buf, 128, 128, 0L, 16384L, 524288L, 0);
  k_mgemm_h<<<dim3(4,64,2), dim3(256), 0, stream>>>(a_buf, xq2, tgt, W1 + 2*131072, h1);
  k_mgemm<<<dim3(2,64,2), dim3(256), 0, stream>>>(h1, W2 + 2*32768, h2, 256, 128, 1048576L, 32768L, 524288L, 1);
  k_w3sm<<<dim3(64,1,2), dim3(256), 0, stream>>>(h2, W3 + 2*128, gb);
  // 9. cluster score + top-k + x_out (fused)
  k_pool<<<dim3(64), dim3(256), 0, stream>>>(gb, x, pidx, outB, outP, outX);
  // 10. per-batch 52x52 blocks of A2
  k_A2<<<dim3(64), dim3(256), 0, stream>>>(A_g, S_g, pidx, outA2);
}